// Round 2
// baseline (1343.586 us; speedup 1.0000x reference)
//
#include <hip/hip_runtime.h>
#include <hip/hip_bf16.h>

#define NROWS 500000
#define DIM   256
#define BSEG  16384
#define LDSP  264              // LDS/image pitch in bf16 elems: 256 + 8 pad
#define NTILE 7813             // ceil(NROWS/64)
#define TILE_B (64 * LDSP * 2) // 33792 bytes per x tile image
#define FGRID 512              // persistent blocks for k_fused2 (2 per CU, LDS-limited)

typedef __attribute__((ext_vector_type(8))) short short8;
typedef __attribute__((ext_vector_type(4))) float floatx4;

// async global->LDS, 16B per lane (wave-uniform LDS base + lane*16)
#define GLD16(gsrc, ldst)                                                      \
  __builtin_amdgcn_global_load_lds(                                            \
      (const __attribute__((address_space(1))) unsigned int*)(gsrc),           \
      (__attribute__((address_space(3))) unsigned int*)(ldst), 16, 0, 0)

// ws layout (bytes):
//   [0,   16M)  local_rep  f32 [BSEG][DIM]
//   [16M, 32M)  global_rep f32 [BSEG][DIM]
//   [32M, 40M)  H1 bf16 [BSEG][DIM]
//   [40M, +128K) W1t  | +128K W2t | +256K W4t   (bf16 k-tiled)
//   [48M, +264M) xbf16 padded tile images [NTILE][64*264]

__device__ __forceinline__ unsigned short f2bf(float f) {
  unsigned u = __float_as_uint(f);
  unsigned r = u + 0x7fffu + ((u >> 16) & 1u);  // RNE
  return (unsigned short)(r >> 16);
}
__device__ __forceinline__ float bf2f(short s) {
  return __uint_as_float(((unsigned)(unsigned short)s) << 16);
}
__device__ __forceinline__ float fast_sigmoid(float z) {
  return 1.0f / (1.0f + __expf(-z));
}
__device__ __forceinline__ int imin(int a, int b) { return a < b ? a : b; }

// One launch: blocks 0-31 convert W1/W2/W4 to k-tiled bf16; blocks 32+ zero reps.
__global__ __launch_bounds__(256) void k_init(
    const float* __restrict__ W1, const float* __restrict__ W2,
    const float* __restrict__ W4, short* __restrict__ W1t,
    short* __restrict__ W2t, short* __restrict__ W4t,
    float* __restrict__ zbase)
{
  int blk = blockIdx.x;
  int n = threadIdx.x;
  if (blk < 32) {
    const float* W; short* out; int kt;
    if (blk < 8)       { W = W1; out = W1t; kt = blk; }
    else if (blk < 16) { W = W2; out = W2t; kt = blk - 8; }
    else               { W = W4; out = W4t; kt = blk - 16; }
    short tmp[32];
#pragma unroll
    for (int kk = 0; kk < 32; ++kk)
      tmp[kk] = (short)f2bf(W[(size_t)(kt * 32 + kk) * DIM + n]);
    size_t base = ((size_t)kt * 256 + n) * 32;
#pragma unroll
    for (int kk = 0; kk < 32; kk += 4)
      *(short4*)&out[base + kk] = *(short4*)&tmp[kk];
  } else {
    // zero local_rep + global_rep: 8192 blocks x 256 float4 = 33.5 MB
    int i = (blk - 32) * 256 + n;
    ((float4*)zbase)[i] = make_float4(0.f, 0.f, 0.f, 0.f);
  }
}

// k_prep2: pure register streaming. Each thread owns 4 columns (c4) x 16 rows
// (strided by 4): load fp32, convert to bf16, store image, and run the masked
// segment-sum in registers. No tile LDS, no hot-path barrier.
__global__ __launch_bounds__(256) void k_prep2(
    const float* __restrict__ x, const int* __restrict__ batch,
    const float* __restrict__ mask, char* __restrict__ xbf16p,
    float* __restrict__ local_rep)
{
  __shared__ int   seg_s[64];
  __shared__ float mask_s[64];
  const int tid = threadIdx.x;
  const int tile = (int)blockIdx.x;
  const int row0 = tile * 64;
  const int g  = tid >> 6;   // wave id -> row phase (rows g, g+4, ..., g+60)
  const int c4 = tid & 63;   // float4 column index

  if (tid < 64) {
    int row = row0 + tid;
    int rowc = imin(row, NROWS - 1);
    seg_s[tid]  = batch[rowc];
    mask_s[tid] = (row < NROWS) ? mask[rowc] : 0.f;  // clamped rows contribute 0
  }
  __syncthreads();

  short* img = (short*)(xbf16p + (size_t)tile * TILE_B);
  float4 acc = make_float4(0.f, 0.f, 0.f, 0.f);
  int cur = seg_s[g];

#pragma unroll
  for (int it = 0; it < 16; ++it) {
    const int r = 4 * it + g;
    const int rowc = imin(row0 + r, NROWS - 1);
    float4 v = *(const float4*)&x[(size_t)rowc * DIM + c4 * 4];
    short4 o;
    o.x = (short)f2bf(v.x); o.y = (short)f2bf(v.y);
    o.z = (short)f2bf(v.z); o.w = (short)f2bf(v.w);
    *(short4*)&img[r * LDSP + c4 * 4] = o;

    int s = seg_s[r];
    float m = mask_s[r];
    if (s != cur) {
      float* dst = &local_rep[(size_t)cur * DIM + c4 * 4];
      atomicAdd(dst + 0, acc.x); atomicAdd(dst + 1, acc.y);
      atomicAdd(dst + 2, acc.z); atomicAdd(dst + 3, acc.w);
      acc = make_float4(0.f, 0.f, 0.f, 0.f);
      cur = s;
    }
    acc.x = fmaf(v.x, m, acc.x); acc.y = fmaf(v.y, m, acc.y);
    acc.z = fmaf(v.z, m, acc.z); acc.w = fmaf(v.w, m, acc.w);
  }
  float* dst = &local_rep[(size_t)cur * DIM + c4 * 4];
  atomicAdd(dst + 0, acc.x); atomicAdd(dst + 1, acc.y);
  atomicAdd(dst + 2, acc.z); atomicAdd(dst + 3, acc.w);
}

// stage 64x256 fp32 tile -> bf16 LDS (pitch LDSP), rows clamped to maxrow
__device__ __forceinline__ void stage_tile(const float* __restrict__ A, int row0,
                                           int maxrow, short* xs, int tid)
{
#pragma unroll
  for (int it = 0; it < 16; ++it) {
    int linear = it * 256 + tid;
    int r = linear >> 6;      // 64 float4 per row
    int c4 = linear & 63;
    int row = imin(row0 + r, maxrow);
    float4 v = *(const float4*)&A[(size_t)row * DIM + c4 * 4];
    short4 o;
    o.x = (short)f2bf(v.x); o.y = (short)f2bf(v.y);
    o.z = (short)f2bf(v.z); o.w = (short)f2bf(v.w);
    *(short4*)&xs[r * LDSP + c4 * 4] = o;
  }
}

// K=256 MFMA pass: acc += xs(64x256 bf16) @ Wt(k-tiled bf16, cols 256)
__device__ __forceinline__ void mfma_pass(const short* xs, const short* __restrict__ Wt,
                                          floatx4 acc[4][4], int lane15, int quad, int n0)
{
  for (int kt = 0; kt < 8; ++kt) {
    short8 bfr[4], afr[4];
#pragma unroll
    for (int jn = 0; jn < 4; ++jn)
      bfr[jn] = *(const short8*)&Wt[(size_t)kt * 8192 + (n0 + jn * 16 + lane15) * 32 + quad * 8];
#pragma unroll
    for (int i = 0; i < 4; ++i)
      afr[i] = *(const short8*)&xs[(i * 16 + lane15) * LDSP + kt * 32 + quad * 8];
#pragma unroll
    for (int i = 0; i < 4; ++i)
#pragma unroll
      for (int jn = 0; jn < 4; ++jn)
        acc[i][jn] = __builtin_amdgcn_mfma_f32_16x16x32_bf16(afr[i], bfr[jn], acc[i][jn], 0, 0, 0);
  }
}

// H1 = bf16(local_rep @ W1 + b1)
__global__ __launch_bounds__(256) void k_h1_mfma(
    const float* __restrict__ A, const short* __restrict__ Wt,
    const float* __restrict__ bias, short* __restrict__ H1bf)
{
  __shared__ __align__(16) short xs[64 * LDSP];
  const int tid = threadIdx.x;
  const int row0 = (int)blockIdx.x * 64;
  stage_tile(A, row0, BSEG - 1, xs, tid);
  __syncthreads();
  const int lane = tid & 63, wave = tid >> 6;
  const int lane15 = lane & 15, quad = lane >> 4;
  const int n0 = wave * 64;
  floatx4 acc[4][4];
#pragma unroll
  for (int i = 0; i < 4; ++i)
#pragma unroll
    for (int j = 0; j < 4; ++j) acc[i][j] = (floatx4)0.f;
  mfma_pass(xs, Wt, acc, lane15, quad, n0);
#pragma unroll
  for (int i = 0; i < 4; ++i)
#pragma unroll
    for (int jn = 0; jn < 4; ++jn) {
      int col = n0 + jn * 16 + lane15;
      float bv = bias[col];
#pragma unroll
      for (int r = 0; r < 4; ++r) {
        int row = row0 + i * 16 + quad * 4 + r;
        H1bf[(size_t)row * DIM + col] = (short)f2bf(acc[i][jn][r] + bv);
      }
    }
}

// Persistent fused main: double-buffered DMA prefetch of the next tile
// overlaps with MFMA + H1 gather + segsum of the current tile.
__global__ __launch_bounds__(256) void k_fused2(
    const char* __restrict__ xbf16p, const int* __restrict__ batch,
    const short* __restrict__ W2t, const float* __restrict__ b2,
    const float* __restrict__ w3, const short* __restrict__ H1bf,
    float* __restrict__ global_rep)
{
  __shared__ __align__(16) short xs[2][64 * LDSP];
  __shared__ int   seg_s[2][64];
  __shared__ float att_s[2][64];
  const int tid = threadIdx.x;
  const int lane = tid & 63, wave = tid >> 6;
  const int lane15 = lane & 15, quad = lane >> 4;
  const int n0 = wave * 64;
  const int bid = (int)blockIdx.x;

  // weights/bias for the epilogue: loop-invariant, hoisted to registers
  float b2v[4], w3v[4];
#pragma unroll
  for (int jn = 0; jn < 4; ++jn) {
    int col = n0 + jn * 16 + lane15;
    b2v[jn] = b2[col];
    w3v[jn] = w3[col];
  }

  // prologue: stage first tile into buffer 0
  {
    const char* gtile = xbf16p + (size_t)bid * TILE_B;
    char* lbase = (char*)&xs[0][0];
#pragma unroll
    for (int j = 0; j < 9; ++j) {
      int c = wave + 4 * j;
      if (c < 33)
        GLD16(gtile + (size_t)c * 1024 + lane * 16, lbase + c * 1024);
    }
    if (tid < 64) {
      seg_s[0][tid] = batch[imin(bid * 64 + tid, NROWS - 1)];
      att_s[0][tid] = 0.f;
    }
  }
  __syncthreads();   // drains vmcnt: buffer 0 ready

  int cur = 0;
  for (int t = bid; t < NTILE; t += FGRID) {
    // ---- stage NEXT tile into the other buffer (overlaps with compute) ----
    const int tn = t + FGRID;
    if (tn < NTILE) {
      const char* gtile = xbf16p + (size_t)tn * TILE_B;
      char* lbase = (char*)&xs[cur ^ 1][0];
#pragma unroll
      for (int j = 0; j < 9; ++j) {
        int c = wave + 4 * j;
        if (c < 33)
          GLD16(gtile + (size_t)c * 1024 + lane * 16, lbase + c * 1024);
      }
      if (tid < 64) {
        seg_s[cur ^ 1][tid] = batch[imin(tn * 64 + tid, NROWS - 1)];
        att_s[cur ^ 1][tid] = 0.f;
      }
    }

    // ---- MFMA on current buffer ----
    floatx4 acc[4][4];
#pragma unroll
    for (int i = 0; i < 4; ++i)
#pragma unroll
      for (int j = 0; j < 4; ++j) acc[i][j] = (floatx4)0.f;
    mfma_pass(&xs[cur][0], W2t, acc, lane15, quad, n0);

    // ---- epilogue: z -> sigmoid -> dot w3 -> att per row ----
    float part[4][4];
#pragma unroll
    for (int i = 0; i < 4; ++i)
#pragma unroll
      for (int r = 0; r < 4; ++r) {
        int rl = i * 16 + quad * 4 + r;
        int seg = seg_s[cur][rl];
        float p = 0.f;
#pragma unroll
        for (int jn = 0; jn < 4; ++jn) {
          int col = n0 + jn * 16 + lane15;
          float h = bf2f(H1bf[(size_t)seg * DIM + col]);
          float z = acc[i][jn][r] + h + b2v[jn];
          p = fmaf(fast_sigmoid(z), w3v[jn], p);
        }
        part[i][r] = p;
      }
#pragma unroll
    for (int off = 1; off < 16; off <<= 1)
#pragma unroll
      for (int i = 0; i < 4; ++i)
#pragma unroll
        for (int r = 0; r < 4; ++r)
          part[i][r] += __shfl_xor(part[i][r], off, 64);
    if (lane15 == 0) {
#pragma unroll
      for (int i = 0; i < 4; ++i)
#pragma unroll
        for (int r = 0; r < 4; ++r)
          atomicAdd(&att_s[cur][i * 16 + quad * 4 + r], part[i][r]);
    }
    __syncthreads();  // att ready (also guarantees next-tile DMA has landed)

    // ---- weighted segsum of x*att from current LDS buffer ----
    {
      const int row0 = t * 64;
      const int col = tid;
      const int rmax = imin(64, NROWS - row0);
      float acc2 = 0.f;
      int sc = seg_s[cur][0];
      for (int r = 0; r < rmax; ++r) {
        int s = seg_s[cur][r];
        float xv = bf2f(xs[cur][r * LDSP + col]);
        float av = att_s[cur][r];
        if (s != sc) {
          atomicAdd(&global_rep[(size_t)sc * DIM + col], acc2);
          acc2 = 0.f; sc = s;
        }
        acc2 = fmaf(xv, av, acc2);
      }
      atomicAdd(&global_rep[(size_t)sc * DIM + col], acc2);
    }
    __syncthreads();  // all reads of xs[cur]/att_s[cur] done; buffer reusable
    cur ^= 1;
  }
}

// out = local_rep @ W4[0:256] + global_rep @ W4[256:512] + b4
__global__ __launch_bounds__(256) void k_out_mfma(
    const float* __restrict__ local_rep, const float* __restrict__ global_rep,
    const short* __restrict__ W4t, const float* __restrict__ b4,
    float* __restrict__ out)
{
  __shared__ __align__(16) short xs[64 * LDSP];
  const int tid = threadIdx.x;
  const int row0 = (int)blockIdx.x * 64;
  const int lane = tid & 63, wave = tid >> 6;
  const int lane15 = lane & 15, quad = lane >> 4;
  const int n0 = wave * 64;
  floatx4 acc[4][4];
#pragma unroll
  for (int i = 0; i < 4; ++i)
#pragma unroll
    for (int j = 0; j < 4; ++j) acc[i][j] = (floatx4)0.f;

  stage_tile(local_rep, row0, BSEG - 1, xs, tid);
  __syncthreads();
  mfma_pass(xs, W4t, acc, lane15, quad, n0);
  __syncthreads();
  stage_tile(global_rep, row0, BSEG - 1, xs, tid);
  __syncthreads();
  mfma_pass(xs, W4t + (size_t)8 * 8192, acc, lane15, quad, n0);

#pragma unroll
  for (int i = 0; i < 4; ++i)
#pragma unroll
    for (int jn = 0; jn < 4; ++jn) {
      int col = n0 + jn * 16 + lane15;
      float bv = b4[col];
#pragma unroll
      for (int r = 0; r < 4; ++r) {
        int row = row0 + i * 16 + quad * 4 + r;
        out[(size_t)row * DIM + col] = acc[i][jn][r] + bv;
      }
    }
}

extern "C" void kernel_launch(void* const* d_in, const int* in_sizes, int n_in,
                              void* d_out, int out_size, void* d_ws, size_t ws_size,
                              hipStream_t stream) {
  (void)in_sizes; (void)n_in; (void)out_size; (void)ws_size;
  const float* x    = (const float*)d_in[0];
  const int*   batch= (const int*)d_in[1];
  const float* mask = (const float*)d_in[2];
  const float* W1 = (const float*)d_in[4];
  const float* b1 = (const float*)d_in[5];
  const float* W2 = (const float*)d_in[6];
  const float* b2 = (const float*)d_in[7];
  const float* w3 = (const float*)d_in[8];
  const float* W4 = (const float*)d_in[9];
  const float* b4 = (const float*)d_in[10];
  float* out = (float*)d_out;

  char* base = (char*)d_ws;
  float* local_rep  = (float*)(base);
  float* global_rep = (float*)(base + (size_t)16 * 1024 * 1024);
  short* H1bf       = (short*)(base + (size_t)32 * 1024 * 1024);
  short* W1t        = (short*)(base + (size_t)40 * 1024 * 1024);
  short* W2t        = (short*)(base + (size_t)40 * 1024 * 1024 + 128 * 1024);
  short* W4t        = (short*)(base + (size_t)40 * 1024 * 1024 + 256 * 1024);
  char*  xbf16p     = base + (size_t)48 * 1024 * 1024;

  // weight conversion (32 blocks) + zero reps (8192 blocks) in one launch
  hipLaunchKernelGGL(k_init, dim3(32 + 8192), dim3(256), 0, stream,
                     W1, W2, W4, W1t, W2t, W4t, local_rep);

  // x -> bf16 tile images + masked segsum, register-streaming
  hipLaunchKernelGGL(k_prep2, dim3(NTILE), dim3(256), 0, stream,
                     x, batch, mask, xbf16p, local_rep);

  hipLaunchKernelGGL(k_h1_mfma, dim3(BSEG / 64), dim3(256), 0, stream,
                     local_rep, W1t, b1, H1bf);

  hipLaunchKernelGGL(k_fused2, dim3(FGRID), dim3(256), 0, stream,
                     xbf16p, batch, W2t, b2, w3, H1bf, global_rep);

  hipLaunchKernelGGL(k_out_mfma, dim3(BSEG / 64), dim3(256), 0, stream,
                     local_rep, global_rep, W4t, b4, out);
}

// Round 3
// 979.893 us; speedup vs baseline: 1.3712x; 1.3712x over previous
//
#include <hip/hip_runtime.h>
#include <hip/hip_bf16.h>

#define NROWS 500000
#define DIM   256
#define BSEG  16384
#define LDSP  264              // LDS pitch in bf16 elems: 256 + 8 pad
#define NTILE 7813             // ceil(NROWS/64)
#define TILE_B (64 * LDSP * 2) // 33792 bytes per x tile image

typedef __attribute__((ext_vector_type(8))) short short8;
typedef __attribute__((ext_vector_type(4))) float floatx4;

// async global->LDS, 16B per lane (wave-uniform LDS base + lane*16)
#define GLD16(gsrc, ldst)                                                      \
  __builtin_amdgcn_global_load_lds(                                            \
      (const __attribute__((address_space(1))) unsigned int*)(gsrc),           \
      (__attribute__((address_space(3))) unsigned int*)(ldst), 16, 0, 0)

// ws layout (bytes):
//   [0,   16M)  local_rep  f32 [BSEG][DIM]
//   [16M, 32M)  global_rep f32 [BSEG][DIM]
//   [32M, 40M)  H1 bf16 [BSEG][DIM]
//   [40M, +128K) W1t  | +128K W2t | +256K W4t   (bf16 k-tiled)
//   [48M, +264M) xbf16 padded tile images [NTILE][64*264]

__device__ __forceinline__ unsigned short f2bf(float f) {
  unsigned u = __float_as_uint(f);
  unsigned r = u + 0x7fffu + ((u >> 16) & 1u);  // RNE
  return (unsigned short)(r >> 16);
}
__device__ __forceinline__ float bf2f(short s) {
  return __uint_as_float(((unsigned)(unsigned short)s) << 16);
}
__device__ __forceinline__ int imin(int a, int b) { return a < b ? a : b; }

// One launch: blocks 0-31 convert W1/W2/W4 to k-tiled bf16; blocks 32+ zero reps.
__global__ __launch_bounds__(256) void k_init(
    const float* __restrict__ W1, const float* __restrict__ W2,
    const float* __restrict__ W4, short* __restrict__ W1t,
    short* __restrict__ W2t, short* __restrict__ W4t,
    float* __restrict__ zbase)
{
  int blk = blockIdx.x;
  int n = threadIdx.x;
  if (blk < 32) {
    const float* W; short* out; int kt;
    if (blk < 8)       { W = W1; out = W1t; kt = blk; }
    else if (blk < 16) { W = W2; out = W2t; kt = blk - 8; }
    else               { W = W4; out = W4t; kt = blk - 16; }
    short tmp[32];
#pragma unroll
    for (int kk = 0; kk < 32; ++kk)
      tmp[kk] = (short)f2bf(W[(size_t)(kt * 32 + kk) * DIM + n]);
    size_t base = ((size_t)kt * 256 + n) * 32;
#pragma unroll
    for (int kk = 0; kk < 32; kk += 4)
      *(short4*)&out[base + kk] = *(short4*)&tmp[kk];
  } else {
    // zero local_rep + global_rep: 8192 blocks x 256 float4 = 33.5 MB
    int i = (blk - 32) * 256 + n;
    ((float4*)zbase)[i] = make_float4(0.f, 0.f, 0.f, 0.f);
  }
}

// stage 64x256 fp32 tile -> bf16 LDS (pitch LDSP), rows clamped to maxrow
__device__ __forceinline__ void stage_tile(const float* __restrict__ A, int row0,
                                           int maxrow, short* xs, int tid)
{
#pragma unroll
  for (int it = 0; it < 16; ++it) {
    int linear = it * 256 + tid;
    int r = linear >> 6;      // 64 float4 per row
    int c4 = linear & 63;
    int row = imin(row0 + r, maxrow);
    float4 v = *(const float4*)&A[(size_t)row * DIM + c4 * 4];
    short4 o;
    o.x = (short)f2bf(v.x); o.y = (short)f2bf(v.y);
    o.z = (short)f2bf(v.z); o.w = (short)f2bf(v.w);
    *(short4*)&xs[r * LDSP + c4 * 4] = o;
  }
}

// k_prep: per 64-row tile: x -> bf16 LDS image -> dump to xbf16p,
// plus masked segment-sum into local_rep (batch sorted).
__global__ __launch_bounds__(256) void k_prep(
    const float* __restrict__ x, const int* __restrict__ batch,
    const float* __restrict__ mask, char* __restrict__ xbf16p,
    float* __restrict__ local_rep)
{
  __shared__ __align__(16) short xs[64 * LDSP];
  __shared__ int   seg_s[64];
  __shared__ float mask_s[64];
  const int tid = threadIdx.x;
  const int tile = (int)blockIdx.x;
  const int row0 = tile * 64;

  stage_tile(x, row0, NROWS - 1, xs, tid);
  if (tid < 64) {
    int row = imin(row0 + tid, NROWS - 1);
    seg_s[tid] = batch[row];
    mask_s[tid] = mask[row];
  }
  __syncthreads();

  // dump LDS image (33792 B = 2112 float4) to global
  float4* g4 = (float4*)(xbf16p + (size_t)tile * TILE_B);
  const float4* l4 = (const float4*)xs;
#pragma unroll
  for (int j = 0; j < 8; ++j)
    g4[j * 256 + tid] = l4[j * 256 + tid];
  if (tid < 64) g4[2048 + tid] = l4[2048 + tid];

  // masked segsum from LDS bf16
  const int col = tid;
  const int rmax = imin(64, NROWS - row0);
  float acc = 0.f;
  int cur = seg_s[0];
  for (int r = 0; r < rmax; ++r) {
    int s = seg_s[r];
    float xv = bf2f(xs[r * LDSP + col]);
    if (s != cur) {
      atomicAdd(&local_rep[(size_t)cur * DIM + col], acc);
      acc = 0.f; cur = s;
    }
    acc = fmaf(xv, mask_s[r], acc);
  }
  atomicAdd(&local_rep[(size_t)cur * DIM + col], acc);
}

// K=256 MFMA pass: acc += xs(64x256 bf16) @ Wt(k-tiled bf16, cols 256)
__device__ __forceinline__ void mfma_pass(const short* xs, const short* __restrict__ Wt,
                                          floatx4 acc[4][4], int lane15, int quad, int n0)
{
  for (int kt = 0; kt < 8; ++kt) {
    short8 bfr[4], afr[4];
#pragma unroll
    for (int jn = 0; jn < 4; ++jn)
      bfr[jn] = *(const short8*)&Wt[(size_t)kt * 8192 + (n0 + jn * 16 + lane15) * 32 + quad * 8];
#pragma unroll
    for (int i = 0; i < 4; ++i)
      afr[i] = *(const short8*)&xs[(i * 16 + lane15) * LDSP + kt * 32 + quad * 8];
#pragma unroll
    for (int i = 0; i < 4; ++i)
#pragma unroll
      for (int jn = 0; jn < 4; ++jn)
        acc[i][jn] = __builtin_amdgcn_mfma_f32_16x16x32_bf16(afr[i], bfr[jn], acc[i][jn], 0, 0, 0);
  }
}

// H1 = bf16(local_rep @ W1 + b1)
__global__ __launch_bounds__(256) void k_h1_mfma(
    const float* __restrict__ A, const short* __restrict__ Wt,
    const float* __restrict__ bias, short* __restrict__ H1bf)
{
  __shared__ __align__(16) short xs[64 * LDSP];
  const int tid = threadIdx.x;
  const int row0 = (int)blockIdx.x * 64;
  stage_tile(A, row0, BSEG - 1, xs, tid);
  __syncthreads();
  const int lane = tid & 63, wave = tid >> 6;
  const int lane15 = lane & 15, quad = lane >> 4;
  const int n0 = wave * 64;
  floatx4 acc[4][4];
#pragma unroll
  for (int i = 0; i < 4; ++i)
#pragma unroll
    for (int j = 0; j < 4; ++j) acc[i][j] = (floatx4)0.f;
  mfma_pass(xs, Wt, acc, lane15, quad, n0);
#pragma unroll
  for (int i = 0; i < 4; ++i)
#pragma unroll
    for (int jn = 0; jn < 4; ++jn) {
      int col = n0 + jn * 16 + lane15;
      float bv = bias[col];
#pragma unroll
      for (int r = 0; r < 4; ++r) {
        int row = row0 + i * 16 + quad * 4 + r;
        H1bf[(size_t)row * DIM + col] = (short)f2bf(acc[i][jn][r] + bv);
      }
    }
}

// Fused: z = x@W2 + b2 + H1[batch]; att = sigmoid(z)@w3; global_rep += segsum(x*att)
// One block per 64-row tile (max inter-block TLP), single LDS buffer, DMA staging.
__global__ __launch_bounds__(256) void k_fused_main(
    const char* __restrict__ xbf16p, const int* __restrict__ batch,
    const short* __restrict__ W2t, const float* __restrict__ b2,
    const float* __restrict__ w3, const short* __restrict__ H1bf,
    float* __restrict__ global_rep)
{
  __shared__ __align__(16) short xs[64 * LDSP];
  __shared__ int   seg_s[64];
  __shared__ float att_s[64];
  const int tid = threadIdx.x;
  const int bid = (int)blockIdx.x;
  const int row0 = bid * 64;
  const int lane = tid & 63, wave = tid >> 6;

  // async DMA the 33792-B tile image: 33 chunks of 1024 B, wave w takes
  // chunks {w, w+4, ...} (wave-uniform LDS base, lane*16 scatter by HW)
  {
    const char* gtile = xbf16p + (size_t)bid * TILE_B;
    char* lbase = (char*)xs;
#pragma unroll
    for (int j = 0; j < 9; ++j) {
      int c = wave + 4 * j;
      if (c < 33)
        GLD16(gtile + (size_t)c * 1024 + lane * 16, lbase + c * 1024);
    }
  }
  if (tid < 64) {
    seg_s[tid] = batch[imin(row0 + tid, NROWS - 1)];
    att_s[tid] = 0.f;
  }
  __syncthreads();   // drains vmcnt (global_load_lds) + lds writes

  const int lane15 = lane & 15, quad = lane >> 4;
  const int n0 = wave * 64;
  floatx4 acc[4][4];
#pragma unroll
  for (int i = 0; i < 4; ++i)
#pragma unroll
    for (int j = 0; j < 4; ++j) acc[i][j] = (floatx4)0.f;
  mfma_pass(xs, W2t, acc, lane15, quad, n0);

  // epilogue: z -> sigmoid -> dot w3 -> att per row
  float b2v[4], w3v[4];
#pragma unroll
  for (int jn = 0; jn < 4; ++jn) {
    int col = n0 + jn * 16 + lane15;
    b2v[jn] = b2[col];
    w3v[jn] = w3[col];
  }
  // seg-cached H1 gather: rl ascending over (i,r) for fixed quad; batch sorted
  // => seg monotone; reload the 4 H1 values only on segment change (~3-5x/thread
  // instead of 16x).
  float part[4][4];
  int prev_seg = -1;
  float h[4] = {0.f, 0.f, 0.f, 0.f};
#pragma unroll
  for (int i = 0; i < 4; ++i)
#pragma unroll
    for (int r = 0; r < 4; ++r) {
      int rl = i * 16 + quad * 4 + r;
      int seg = seg_s[rl];
      if (seg != prev_seg) {
#pragma unroll
        for (int jn = 0; jn < 4; ++jn)
          h[jn] = bf2f(H1bf[(size_t)seg * DIM + n0 + jn * 16 + lane15]);
        prev_seg = seg;
      }
      float p = 0.f;
#pragma unroll
      for (int jn = 0; jn < 4; ++jn) {
        float z = acc[i][jn][r] + h[jn] + b2v[jn];
        // sigmoid via v_exp + v_rcp (approx rcp: error ~1ulp, tolerance 0.0625)
        float sg = __builtin_amdgcn_rcpf(1.0f + __expf(-z));
        p = fmaf(sg, w3v[jn], p);
      }
      part[i][r] = p;
    }
  // reduce over the 16 lanes (cols) of each quad
#pragma unroll
  for (int off = 1; off < 16; off <<= 1)
#pragma unroll
    for (int i = 0; i < 4; ++i)
#pragma unroll
      for (int r = 0; r < 4; ++r)
        part[i][r] += __shfl_xor(part[i][r], off, 64);
  if (lane15 == 0) {
#pragma unroll
    for (int i = 0; i < 4; ++i)
#pragma unroll
      for (int r = 0; r < 4; ++r)
        atomicAdd(&att_s[i * 16 + quad * 4 + r], part[i][r]);
  }
  __syncthreads();

  // phase 2: weighted segsum of x*att from LDS (bf16 x)
  const int col = tid;
  const int rmax = imin(64, NROWS - row0);
  float acc2 = 0.f;
  int cur = seg_s[0];
  for (int r = 0; r < rmax; ++r) {
    int s = seg_s[r];
    float xv = bf2f(xs[r * LDSP + col]);
    float av = att_s[r];
    if (s != cur) {
      atomicAdd(&global_rep[(size_t)cur * DIM + col], acc2);
      acc2 = 0.f; cur = s;
    }
    acc2 = fmaf(xv, av, acc2);
  }
  atomicAdd(&global_rep[(size_t)cur * DIM + col], acc2);
}

// out = local_rep @ W4[0:256] + global_rep @ W4[256:512] + b4
__global__ __launch_bounds__(256) void k_out_mfma(
    const float* __restrict__ local_rep, const float* __restrict__ global_rep,
    const short* __restrict__ W4t, const float* __restrict__ b4,
    float* __restrict__ out)
{
  __shared__ __align__(16) short xs[64 * LDSP];
  const int tid = threadIdx.x;
  const int row0 = (int)blockIdx.x * 64;
  const int lane = tid & 63, wave = tid >> 6;
  const int lane15 = lane & 15, quad = lane >> 4;
  const int n0 = wave * 64;
  floatx4 acc[4][4];
#pragma unroll
  for (int i = 0; i < 4; ++i)
#pragma unroll
    for (int j = 0; j < 4; ++j) acc[i][j] = (floatx4)0.f;

  stage_tile(local_rep, row0, BSEG - 1, xs, tid);
  __syncthreads();
  mfma_pass(xs, W4t, acc, lane15, quad, n0);
  __syncthreads();
  stage_tile(global_rep, row0, BSEG - 1, xs, tid);
  __syncthreads();
  mfma_pass(xs, W4t + (size_t)8 * 8192, acc, lane15, quad, n0);

#pragma unroll
  for (int i = 0; i < 4; ++i)
#pragma unroll
    for (int jn = 0; jn < 4; ++jn) {
      int col = n0 + jn * 16 + lane15;
      float bv = b4[col];
#pragma unroll
      for (int r = 0; r < 4; ++r) {
        int row = row0 + i * 16 + quad * 4 + r;
        out[(size_t)row * DIM + col] = acc[i][jn][r] + bv;
      }
    }
}

extern "C" void kernel_launch(void* const* d_in, const int* in_sizes, int n_in,
                              void* d_out, int out_size, void* d_ws, size_t ws_size,
                              hipStream_t stream) {
  (void)in_sizes; (void)n_in; (void)out_size; (void)ws_size;
  const float* x    = (const float*)d_in[0];
  const int*   batch= (const int*)d_in[1];
  const float* mask = (const float*)d_in[2];
  const float* W1 = (const float*)d_in[4];
  const float* b1 = (const float*)d_in[5];
  const float* W2 = (const float*)d_in[6];
  const float* b2 = (const float*)d_in[7];
  const float* w3 = (const float*)d_in[8];
  const float* W4 = (const float*)d_in[9];
  const float* b4 = (const float*)d_in[10];
  float* out = (float*)d_out;

  char* base = (char*)d_ws;
  float* local_rep  = (float*)(base);
  float* global_rep = (float*)(base + (size_t)16 * 1024 * 1024);
  short* H1bf       = (short*)(base + (size_t)32 * 1024 * 1024);
  short* W1t        = (short*)(base + (size_t)40 * 1024 * 1024);
  short* W2t        = (short*)(base + (size_t)40 * 1024 * 1024 + 128 * 1024);
  short* W4t        = (short*)(base + (size_t)40 * 1024 * 1024 + 256 * 1024);
  char*  xbf16p     = base + (size_t)48 * 1024 * 1024;

  // weight conversion (32 blocks) + zero reps (8192 blocks) in one launch
  hipLaunchKernelGGL(k_init, dim3(32 + 8192), dim3(256), 0, stream,
                     W1, W2, W4, W1t, W2t, W4t, local_rep);

  // x -> bf16 tile images + masked segsum
  hipLaunchKernelGGL(k_prep, dim3(NTILE), dim3(256), 0, stream,
                     x, batch, mask, xbf16p, local_rep);

  hipLaunchKernelGGL(k_h1_mfma, dim3(BSEG / 64), dim3(256), 0, stream,
                     local_rep, W1t, b1, H1bf);

  hipLaunchKernelGGL(k_fused_main, dim3(NTILE), dim3(256), 0, stream,
                     xbf16p, batch, W2t, b2, w3, H1bf, global_rep);

  hipLaunchKernelGGL(k_out_mfma, dim3(BSEG / 64), dim3(256), 0, stream,
                     local_rep, global_rep, W4t, b4, out);
}

// Round 4
// 960.431 us; speedup vs baseline: 1.3989x; 1.0203x over previous
//
#include <hip/hip_runtime.h>
#include <hip/hip_bf16.h>

#define NROWS 500000
#define DIM   256
#define BSEG  16384
#define LDSP  264                // pitch in bf16 elems: 256 + 8 pad (bank spread)
#define NT32  15625              // 500000 / 32 exactly -> no partial tiles
#define TILE32_B 17408           // 32*LDSP*2 = 16896, padded to 17*1024 for DMA

typedef __attribute__((ext_vector_type(8))) short short8;
typedef __attribute__((ext_vector_type(4))) float floatx4;

// async global->LDS, 16B per lane (wave-uniform LDS base + lane*16)
#define GLD16(gsrc, ldst)                                                      \
  __builtin_amdgcn_global_load_lds(                                            \
      (const __attribute__((address_space(1))) unsigned int*)(gsrc),           \
      (__attribute__((address_space(3))) unsigned int*)(ldst), 16, 0, 0)

// ws layout (bytes):
//   [0,   16M)  local_rep  f32 [BSEG][DIM]
//   [16M, 32M)  global_rep f32 [BSEG][DIM]
//   [32M, 40M)  H1 bf16 [BSEG][DIM]
//   [40M, +128K) W1t  | +128K W2t | +256K W4t   (bf16 k-tiled)
//   [48M, +272M) xbf16 padded tile images [NT32][17408 B]

__device__ __forceinline__ unsigned short f2bf(float f) {
  unsigned u = __float_as_uint(f);
  unsigned r = u + 0x7fffu + ((u >> 16) & 1u);  // RNE
  return (unsigned short)(r >> 16);
}
__device__ __forceinline__ float bf2f(short s) {
  return __uint_as_float(((unsigned)(unsigned short)s) << 16);
}
__device__ __forceinline__ int imin(int a, int b) { return a < b ? a : b; }

// One launch: blocks 0-31 convert W1/W2/W4 to k-tiled bf16; blocks 32+ zero reps.
__global__ __launch_bounds__(256) void k_init(
    const float* __restrict__ W1, const float* __restrict__ W2,
    const float* __restrict__ W4, short* __restrict__ W1t,
    short* __restrict__ W2t, short* __restrict__ W4t,
    float* __restrict__ zbase)
{
  int blk = blockIdx.x;
  int n = threadIdx.x;
  if (blk < 32) {
    const float* W; short* out; int kt;
    if (blk < 8)       { W = W1; out = W1t; kt = blk; }
    else if (blk < 16) { W = W2; out = W2t; kt = blk - 8; }
    else               { W = W4; out = W4t; kt = blk - 16; }
    short tmp[32];
#pragma unroll
    for (int kk = 0; kk < 32; ++kk)
      tmp[kk] = (short)f2bf(W[(size_t)(kt * 32 + kk) * DIM + n]);
    size_t base = ((size_t)kt * 256 + n) * 32;
#pragma unroll
    for (int kk = 0; kk < 32; kk += 4)
      *(short4*)&out[base + kk] = *(short4*)&tmp[kk];
  } else {
    // zero local_rep + global_rep: 8192 blocks x 256 float4 = 33.5 MB
    int i = (blk - 32) * 256 + n;
    ((float4*)zbase)[i] = make_float4(0.f, 0.f, 0.f, 0.f);
  }
}

// k_prep32: 32-row tile. Load x fp32 (coalesced), convert, write bf16 image
// DIRECTLY to global from registers AND to LDS (transpose buffer), then the
// column-serial masked segsum (32 iters). No dump phase, 17 KB LDS.
__global__ __launch_bounds__(256, 6) void k_prep32(
    const float* __restrict__ x, const int* __restrict__ batch,
    const float* __restrict__ mask, char* __restrict__ xbf16p,
    float* __restrict__ local_rep)
{
  __shared__ __align__(16) short xs[32 * LDSP];
  __shared__ int   seg_s[32];
  __shared__ float mask_s[32];
  const int tid = threadIdx.x;
  const int tile = (int)blockIdx.x;
  const int row0 = tile * 32;

  if (tid < 32) {
    seg_s[tid]  = batch[row0 + tid];
    mask_s[tid] = mask[row0 + tid];
  }
  short* img = (short*)(xbf16p + (size_t)tile * TILE32_B);
#pragma unroll
  for (int it = 0; it < 8; ++it) {
    int linear = it * 256 + tid;
    int r  = linear >> 6;     // 0..31
    int c4 = linear & 63;
    float4 v = *(const float4*)&x[(size_t)(row0 + r) * DIM + c4 * 4];
    short4 o;
    o.x = (short)f2bf(v.x); o.y = (short)f2bf(v.y);
    o.z = (short)f2bf(v.z); o.w = (short)f2bf(v.w);
    *(short4*)&xs[r * LDSP + c4 * 4] = o;
    *(short4*)&img[r * LDSP + c4 * 4] = o;   // same linear layout as LDS
  }
  __syncthreads();

  // masked segsum from LDS bf16 (column col = tid, 32 rows)
  const int col = tid;
  float acc = 0.f;
  int cur = seg_s[0];
  for (int r = 0; r < 32; ++r) {
    int s = seg_s[r];
    float xv = bf2f(xs[r * LDSP + col]);
    if (s != cur) {
      atomicAdd(&local_rep[(size_t)cur * DIM + col], acc);
      acc = 0.f; cur = s;
    }
    acc = fmaf(xv, mask_s[r], acc);
  }
  atomicAdd(&local_rep[(size_t)cur * DIM + col], acc);
}

// stage 64x256 fp32 tile -> bf16 LDS (pitch LDSP), rows clamped to maxrow
__device__ __forceinline__ void stage_tile(const float* __restrict__ A, int row0,
                                           int maxrow, short* xs, int tid)
{
#pragma unroll
  for (int it = 0; it < 16; ++it) {
    int linear = it * 256 + tid;
    int r = linear >> 6;      // 64 float4 per row
    int c4 = linear & 63;
    int row = imin(row0 + r, maxrow);
    float4 v = *(const float4*)&A[(size_t)row * DIM + c4 * 4];
    short4 o;
    o.x = (short)f2bf(v.x); o.y = (short)f2bf(v.y);
    o.z = (short)f2bf(v.z); o.w = (short)f2bf(v.w);
    *(short4*)&xs[r * LDSP + c4 * 4] = o;
  }
}

// K=256 MFMA pass over 64 rows: acc += xs(64x256) @ Wt
__device__ __forceinline__ void mfma_pass(const short* xs, const short* __restrict__ Wt,
                                          floatx4 acc[4][4], int lane15, int quad, int n0)
{
  for (int kt = 0; kt < 8; ++kt) {
    short8 bfr[4], afr[4];
#pragma unroll
    for (int jn = 0; jn < 4; ++jn)
      bfr[jn] = *(const short8*)&Wt[(size_t)kt * 8192 + (n0 + jn * 16 + lane15) * 32 + quad * 8];
#pragma unroll
    for (int i = 0; i < 4; ++i)
      afr[i] = *(const short8*)&xs[(i * 16 + lane15) * LDSP + kt * 32 + quad * 8];
#pragma unroll
    for (int i = 0; i < 4; ++i)
#pragma unroll
      for (int jn = 0; jn < 4; ++jn)
        acc[i][jn] = __builtin_amdgcn_mfma_f32_16x16x32_bf16(afr[i], bfr[jn], acc[i][jn], 0, 0, 0);
  }
}

// K=256 MFMA pass over 32 rows: acc += xs(32x256) @ Wt
__device__ __forceinline__ void mfma_pass32(const short* xs, const short* __restrict__ Wt,
                                            floatx4 acc[2][4], int lane15, int quad, int n0)
{
  for (int kt = 0; kt < 8; ++kt) {
    short8 bfr[4], afr[2];
#pragma unroll
    for (int jn = 0; jn < 4; ++jn)
      bfr[jn] = *(const short8*)&Wt[(size_t)kt * 8192 + (n0 + jn * 16 + lane15) * 32 + quad * 8];
#pragma unroll
    for (int i = 0; i < 2; ++i)
      afr[i] = *(const short8*)&xs[(i * 16 + lane15) * LDSP + kt * 32 + quad * 8];
#pragma unroll
    for (int i = 0; i < 2; ++i)
#pragma unroll
      for (int jn = 0; jn < 4; ++jn)
        acc[i][jn] = __builtin_amdgcn_mfma_f32_16x16x32_bf16(afr[i], bfr[jn], acc[i][jn], 0, 0, 0);
  }
}

// H1 = bf16(local_rep @ W1 + b1)
__global__ __launch_bounds__(256) void k_h1_mfma(
    const float* __restrict__ A, const short* __restrict__ Wt,
    const float* __restrict__ bias, short* __restrict__ H1bf)
{
  __shared__ __align__(16) short xs[64 * LDSP];
  const int tid = threadIdx.x;
  const int row0 = (int)blockIdx.x * 64;
  stage_tile(A, row0, BSEG - 1, xs, tid);
  __syncthreads();
  const int lane = tid & 63, wave = tid >> 6;
  const int lane15 = lane & 15, quad = lane >> 4;
  const int n0 = wave * 64;
  floatx4 acc[4][4];
#pragma unroll
  for (int i = 0; i < 4; ++i)
#pragma unroll
    for (int j = 0; j < 4; ++j) acc[i][j] = (floatx4)0.f;
  mfma_pass(xs, Wt, acc, lane15, quad, n0);
#pragma unroll
  for (int i = 0; i < 4; ++i)
#pragma unroll
    for (int jn = 0; jn < 4; ++jn) {
      int col = n0 + jn * 16 + lane15;
      float bv = bias[col];
#pragma unroll
      for (int r = 0; r < 4; ++r) {
        int row = row0 + i * 16 + quad * 4 + r;
        H1bf[(size_t)row * DIM + col] = (short)f2bf(acc[i][jn][r] + bv);
      }
    }
}

// Fused 32-row tile: z = x@W2 + b2 + H1[batch]; att = sigmoid(z)@w3;
// global_rep += segsum(x*att). 17 KB LDS, target 5 blocks/CU.
__global__ __launch_bounds__(256, 5) void k_fused32(
    const char* __restrict__ xbf16p, const int* __restrict__ batch,
    const short* __restrict__ W2t, const float* __restrict__ b2,
    const float* __restrict__ w3, const short* __restrict__ H1bf,
    float* __restrict__ global_rep)
{
  __shared__ __align__(16) short xs[TILE32_B / 2];  // 17408 B incl 512 B DMA pad
  __shared__ int   seg_s[32];
  __shared__ float att_s[32];
  const int tid = threadIdx.x;
  const int bid = (int)blockIdx.x;
  const int row0 = bid * 32;
  const int lane = tid & 63, wave = tid >> 6;
  const int lane15 = lane & 15, quad = lane >> 4;
  const int n0 = wave * 64;

  // async DMA the 17408-B padded tile image: 17 chunks of 1024 B
  {
    const char* gtile = xbf16p + (size_t)bid * TILE32_B;
    char* lbase = (char*)xs;
#pragma unroll
    for (int j = 0; j < 5; ++j) {
      int c = wave + 4 * j;
      if (c < 17)
        GLD16(gtile + (size_t)c * 1024 + lane * 16, lbase + c * 1024);
    }
  }
  if (tid < 32) {
    seg_s[tid] = batch[row0 + tid];
    att_s[tid] = 0.f;
  }
  // hoist loop-invariant epilogue inputs (independent of DMA)
  float b2v[4], w3v[4];
#pragma unroll
  for (int jn = 0; jn < 4; ++jn) {
    int col = n0 + jn * 16 + lane15;
    b2v[jn] = b2[col];
    w3v[jn] = w3[col];
  }
  __syncthreads();   // drains vmcnt (global_load_lds) + lds writes

  // prefetch H1 for this thread's first segment; hides under MFMA
  int prev_seg = seg_s[quad * 4];
  float h[4];
#pragma unroll
  for (int jn = 0; jn < 4; ++jn)
    h[jn] = bf2f(H1bf[(size_t)prev_seg * DIM + n0 + jn * 16 + lane15]);

  floatx4 acc[2][4];
#pragma unroll
  for (int i = 0; i < 2; ++i)
#pragma unroll
    for (int j = 0; j < 4; ++j) acc[i][j] = (floatx4)0.f;
  mfma_pass32(xs, W2t, acc, lane15, quad, n0);

  // epilogue: z -> sigmoid -> dot w3 -> att per row (seg-cached H1 gather)
  float part[2][4];
#pragma unroll
  for (int i = 0; i < 2; ++i)
#pragma unroll
    for (int r = 0; r < 4; ++r) {
      int rl = i * 16 + quad * 4 + r;
      int seg = seg_s[rl];
      if (seg != prev_seg) {
#pragma unroll
        for (int jn = 0; jn < 4; ++jn)
          h[jn] = bf2f(H1bf[(size_t)seg * DIM + n0 + jn * 16 + lane15]);
        prev_seg = seg;
      }
      float p = 0.f;
#pragma unroll
      for (int jn = 0; jn < 4; ++jn) {
        float z = acc[i][jn][r] + h[jn] + b2v[jn];
        float sg = __builtin_amdgcn_rcpf(1.0f + __expf(-z));
        p = fmaf(sg, w3v[jn], p);
      }
      part[i][r] = p;
    }
  // reduce over the 16 lanes (cols) of each quad
#pragma unroll
  for (int off = 1; off < 16; off <<= 1)
#pragma unroll
    for (int i = 0; i < 2; ++i)
#pragma unroll
      for (int r = 0; r < 4; ++r)
        part[i][r] += __shfl_xor(part[i][r], off, 64);
  if (lane15 == 0) {
#pragma unroll
    for (int i = 0; i < 2; ++i)
#pragma unroll
      for (int r = 0; r < 4; ++r)
        atomicAdd(&att_s[i * 16 + quad * 4 + r], part[i][r]);
  }
  __syncthreads();

  // phase 2: weighted segsum of x*att from LDS (bf16 x), 32 rows
  const int col = tid;
  float acc2 = 0.f;
  int cur = seg_s[0];
  for (int r = 0; r < 32; ++r) {
    int s = seg_s[r];
    float xv = bf2f(xs[r * LDSP + col]);
    float av = att_s[r];
    if (s != cur) {
      atomicAdd(&global_rep[(size_t)cur * DIM + col], acc2);
      acc2 = 0.f; cur = s;
    }
    acc2 = fmaf(xv, av, acc2);
  }
  atomicAdd(&global_rep[(size_t)cur * DIM + col], acc2);
}

// out = local_rep @ W4[0:256] + global_rep @ W4[256:512] + b4
__global__ __launch_bounds__(256) void k_out_mfma(
    const float* __restrict__ local_rep, const float* __restrict__ global_rep,
    const short* __restrict__ W4t, const float* __restrict__ b4,
    float* __restrict__ out)
{
  __shared__ __align__(16) short xs[64 * LDSP];
  const int tid = threadIdx.x;
  const int row0 = (int)blockIdx.x * 64;
  const int lane = tid & 63, wave = tid >> 6;
  const int lane15 = lane & 15, quad = lane >> 4;
  const int n0 = wave * 64;
  floatx4 acc[4][4];
#pragma unroll
  for (int i = 0; i < 4; ++i)
#pragma unroll
    for (int j = 0; j < 4; ++j) acc[i][j] = (floatx4)0.f;

  stage_tile(local_rep, row0, BSEG - 1, xs, tid);
  __syncthreads();
  mfma_pass(xs, W4t, acc, lane15, quad, n0);
  __syncthreads();
  stage_tile(global_rep, row0, BSEG - 1, xs, tid);
  __syncthreads();
  mfma_pass(xs, W4t + (size_t)8 * 8192, acc, lane15, quad, n0);

#pragma unroll
  for (int i = 0; i < 4; ++i)
#pragma unroll
    for (int jn = 0; jn < 4; ++jn) {
      int col = n0 + jn * 16 + lane15;
      float bv = b4[col];
#pragma unroll
      for (int r = 0; r < 4; ++r) {
        int row = row0 + i * 16 + quad * 4 + r;
        out[(size_t)row * DIM + col] = acc[i][jn][r] + bv;
      }
    }
}

extern "C" void kernel_launch(void* const* d_in, const int* in_sizes, int n_in,
                              void* d_out, int out_size, void* d_ws, size_t ws_size,
                              hipStream_t stream) {
  (void)in_sizes; (void)n_in; (void)out_size; (void)ws_size;
  const float* x    = (const float*)d_in[0];
  const int*   batch= (const int*)d_in[1];
  const float* mask = (const float*)d_in[2];
  const float* W1 = (const float*)d_in[4];
  const float* b1 = (const float*)d_in[5];
  const float* W2 = (const float*)d_in[6];
  const float* b2 = (const float*)d_in[7];
  const float* w3 = (const float*)d_in[8];
  const float* W4 = (const float*)d_in[9];
  const float* b4 = (const float*)d_in[10];
  float* out = (float*)d_out;

  char* base = (char*)d_ws;
  float* local_rep  = (float*)(base);
  float* global_rep = (float*)(base + (size_t)16 * 1024 * 1024);
  short* H1bf       = (short*)(base + (size_t)32 * 1024 * 1024);
  short* W1t        = (short*)(base + (size_t)40 * 1024 * 1024);
  short* W2t        = (short*)(base + (size_t)40 * 1024 * 1024 + 128 * 1024);
  short* W4t        = (short*)(base + (size_t)40 * 1024 * 1024 + 256 * 1024);
  char*  xbf16p     = base + (size_t)48 * 1024 * 1024;

  // weight conversion (32 blocks) + zero reps (8192 blocks) in one launch
  hipLaunchKernelGGL(k_init, dim3(32 + 8192), dim3(256), 0, stream,
                     W1, W2, W4, W1t, W2t, W4t, local_rep);

  // x -> bf16 tile images (direct from regs) + masked segsum, 32-row tiles
  hipLaunchKernelGGL(k_prep32, dim3(NT32), dim3(256), 0, stream,
                     x, batch, mask, xbf16p, local_rep);

  hipLaunchKernelGGL(k_h1_mfma, dim3(BSEG / 64), dim3(256), 0, stream,
                     local_rep, W1t, b1, H1bf);

  hipLaunchKernelGGL(k_fused32, dim3(NT32), dim3(256), 0, stream,
                     xbf16p, batch, W2t, b2, w3, H1bf, global_rep);

  hipLaunchKernelGGL(k_out_mfma, dim3(BSEG / 64), dim3(256), 0, stream,
                     local_rep, global_rep, W4t, b4, out);
}

// Round 5
// 946.346 us; speedup vs baseline: 1.4198x; 1.0149x over previous
//
#include <hip/hip_runtime.h>
#include <hip/hip_bf16.h>

#define NROWS 500000
#define DIM   256
#define BSEG  16384
#define LDSP  264                // pitch in bf16 elems: 256 + 8 pad (bank spread)
#define NT32  15625              // 500000 / 32 exactly -> no partial tiles
#define TILE32_B 17408           // 32*LDSP*2 = 16896, padded to 17*1024 for DMA

typedef __attribute__((ext_vector_type(8))) short short8;
typedef __attribute__((ext_vector_type(4))) float floatx4;

// async global->LDS, 16B per lane (wave-uniform LDS base + lane*16)
#define GLD16(gsrc, ldst)                                                      \
  __builtin_amdgcn_global_load_lds(                                            \
      (const __attribute__((address_space(1))) unsigned int*)(gsrc),           \
      (__attribute__((address_space(3))) unsigned int*)(ldst), 16, 0, 0)

// ws layout (bytes):
//   [0,   16M)  local_rep  f32 [BSEG][DIM]
//   [16M, 32M)  global_rep f32 [BSEG][DIM]
//   [32M, 40M)  H1 bf16 [BSEG][DIM]
//   [40M, +128K) W1t  | +128K W2t | +256K W4t   (bf16 k-tiled)
//   [48M, +272M) xbf16 padded tile images [NT32][17408 B]

__device__ __forceinline__ unsigned short f2bf(float f) {
  unsigned u = __float_as_uint(f);
  unsigned r = u + 0x7fffu + ((u >> 16) & 1u);  // RNE
  return (unsigned short)(r >> 16);
}
__device__ __forceinline__ float bf2f(short s) {
  return __uint_as_float(((unsigned)(unsigned short)s) << 16);
}
__device__ __forceinline__ int imin(int a, int b) { return a < b ? a : b; }

// flush one segment-column partial: plain store if this tile is the only
// writer of this segment (segment interior to tile), else atomicAdd.
__device__ __forceinline__ void seg_flush(float* __restrict__ rep, int seg,
                                          int col, float v, int segprev,
                                          int segnext) {
  float* p = &rep[(size_t)seg * DIM + col];
  if (seg == segprev || seg == segnext) atomicAdd(p, v);
  else *p = v;   // rep was zero-initialized; unique writer
}

// k_init: 32 blocks, weight conversion only (zeroing moved to hipMemsetAsync)
__global__ __launch_bounds__(256) void k_init(
    const float* __restrict__ W1, const float* __restrict__ W2,
    const float* __restrict__ W4, short* __restrict__ W1t,
    short* __restrict__ W2t, short* __restrict__ W4t)
{
  int blk = blockIdx.x;
  int n = threadIdx.x;
  const float* W; short* out; int kt;
  if (blk < 8)       { W = W1; out = W1t; kt = blk; }
  else if (blk < 16) { W = W2; out = W2t; kt = blk - 8; }
  else               { W = W4; out = W4t; kt = blk - 16; }
  short tmp[32];
#pragma unroll
  for (int kk = 0; kk < 32; ++kk)
    tmp[kk] = (short)f2bf(W[(size_t)(kt * 32 + kk) * DIM + n]);
  size_t base = ((size_t)kt * 256 + n) * 32;
#pragma unroll
  for (int kk = 0; kk < 32; kk += 4)
    *(short4*)&out[base + kk] = *(short4*)&tmp[kk];
}

// k_prep32: 32-row tile. Load x fp32 (coalesced), convert, write bf16 image
// directly from registers AND to LDS, then the column-serial masked segsum
// driven by a uniform boundary bitmask (no per-row seg_s LDS reads).
__global__ __launch_bounds__(256, 6) void k_prep32(
    const float* __restrict__ x, const int* __restrict__ batch,
    const float* __restrict__ mask, char* __restrict__ xbf16p,
    float* __restrict__ local_rep)
{
  __shared__ __align__(16) short xs[32 * LDSP];
  __shared__ int   seg_s[32];
  __shared__ float mask_s[32];
  const int tid = threadIdx.x;
  const int lane = tid & 63;
  const int tile = (int)blockIdx.x;
  const int row0 = tile * 32;

  if (tid < 32) {
    seg_s[tid]  = batch[row0 + tid];
    mask_s[tid] = mask[row0 + tid];
  }
  const int segprev = (row0 > 0) ? batch[row0 - 1] : -1;
  const int segnext = (row0 + 32 < NROWS) ? batch[row0 + 32] : -1;

  short* img = (short*)(xbf16p + (size_t)tile * TILE32_B);
#pragma unroll
  for (int it = 0; it < 8; ++it) {
    int linear = it * 256 + tid;
    int r  = linear >> 6;     // 0..31
    int c4 = linear & 63;
    float4 v = *(const float4*)&x[(size_t)(row0 + r) * DIM + c4 * 4];
    short4 o;
    o.x = (short)f2bf(v.x); o.y = (short)f2bf(v.y);
    o.z = (short)f2bf(v.z); o.w = (short)f2bf(v.w);
    *(short4*)&xs[r * LDSP + c4 * 4] = o;
    *(short4*)&img[r * LDSP + c4 * 4] = o;   // same linear layout as LDS
  }
  __syncthreads();

  // uniform 32-bit boundary mask (bit r set iff seg changes at row r)
  unsigned bmask = (unsigned)__ballot(lane > 0 && lane < 32 &&
                                      seg_s[lane] != seg_s[lane - 1]);

  // masked segsum from LDS bf16 (column col = tid, 32 rows)
  const int col = tid;
  float acc = 0.f;
  int cur = seg_s[0];
#pragma unroll
  for (int r = 0; r < 32; ++r) {
    if (bmask & (1u << r)) {         // uniform branch, rare
      seg_flush(local_rep, cur, col, acc, segprev, segnext);
      acc = 0.f; cur = seg_s[r];
    }
    acc = fmaf(bf2f(xs[r * LDSP + col]), mask_s[r], acc);
  }
  seg_flush(local_rep, cur, col, acc, segprev, segnext);
}

// stage 64x256 fp32 tile -> bf16 LDS (pitch LDSP), rows clamped to maxrow
__device__ __forceinline__ void stage_tile(const float* __restrict__ A, int row0,
                                           int maxrow, short* xs, int tid)
{
#pragma unroll
  for (int it = 0; it < 16; ++it) {
    int linear = it * 256 + tid;
    int r = linear >> 6;      // 64 float4 per row
    int c4 = linear & 63;
    int row = imin(row0 + r, maxrow);
    float4 v = *(const float4*)&A[(size_t)row * DIM + c4 * 4];
    short4 o;
    o.x = (short)f2bf(v.x); o.y = (short)f2bf(v.y);
    o.z = (short)f2bf(v.z); o.w = (short)f2bf(v.w);
    *(short4*)&xs[r * LDSP + c4 * 4] = o;
  }
}

// K=256 MFMA pass over 64 rows: acc += xs(64x256) @ Wt
__device__ __forceinline__ void mfma_pass(const short* xs, const short* __restrict__ Wt,
                                          floatx4 acc[4][4], int lane15, int quad, int n0)
{
  for (int kt = 0; kt < 8; ++kt) {
    short8 bfr[4], afr[4];
#pragma unroll
    for (int jn = 0; jn < 4; ++jn)
      bfr[jn] = *(const short8*)&Wt[(size_t)kt * 8192 + (n0 + jn * 16 + lane15) * 32 + quad * 8];
#pragma unroll
    for (int i = 0; i < 4; ++i)
      afr[i] = *(const short8*)&xs[(i * 16 + lane15) * LDSP + kt * 32 + quad * 8];
#pragma unroll
    for (int i = 0; i < 4; ++i)
#pragma unroll
      for (int jn = 0; jn < 4; ++jn)
        acc[i][jn] = __builtin_amdgcn_mfma_f32_16x16x32_bf16(afr[i], bfr[jn], acc[i][jn], 0, 0, 0);
  }
}

// K=256 MFMA pass over 32 rows: acc += xs(32x256) @ Wt
__device__ __forceinline__ void mfma_pass32(const short* xs, const short* __restrict__ Wt,
                                            floatx4 acc[2][4], int lane15, int quad, int n0)
{
  for (int kt = 0; kt < 8; ++kt) {
    short8 bfr[4], afr[2];
#pragma unroll
    for (int jn = 0; jn < 4; ++jn)
      bfr[jn] = *(const short8*)&Wt[(size_t)kt * 8192 + (n0 + jn * 16 + lane15) * 32 + quad * 8];
#pragma unroll
    for (int i = 0; i < 2; ++i)
      afr[i] = *(const short8*)&xs[(i * 16 + lane15) * LDSP + kt * 32 + quad * 8];
#pragma unroll
    for (int i = 0; i < 2; ++i)
#pragma unroll
      for (int jn = 0; jn < 4; ++jn)
        acc[i][jn] = __builtin_amdgcn_mfma_f32_16x16x32_bf16(afr[i], bfr[jn], acc[i][jn], 0, 0, 0);
  }
}

// H1 = bf16(local_rep @ W1 + b1)
__global__ __launch_bounds__(256) void k_h1_mfma(
    const float* __restrict__ A, const short* __restrict__ Wt,
    const float* __restrict__ bias, short* __restrict__ H1bf)
{
  __shared__ __align__(16) short xs[64 * LDSP];
  const int tid = threadIdx.x;
  const int row0 = (int)blockIdx.x * 64;
  stage_tile(A, row0, BSEG - 1, xs, tid);
  __syncthreads();
  const int lane = tid & 63, wave = tid >> 6;
  const int lane15 = lane & 15, quad = lane >> 4;
  const int n0 = wave * 64;
  floatx4 acc[4][4];
#pragma unroll
  for (int i = 0; i < 4; ++i)
#pragma unroll
    for (int j = 0; j < 4; ++j) acc[i][j] = (floatx4)0.f;
  mfma_pass(xs, Wt, acc, lane15, quad, n0);
#pragma unroll
  for (int i = 0; i < 4; ++i)
#pragma unroll
    for (int jn = 0; jn < 4; ++jn) {
      int col = n0 + jn * 16 + lane15;
      float bv = bias[col];
#pragma unroll
      for (int r = 0; r < 4; ++r) {
        int row = row0 + i * 16 + quad * 4 + r;
        H1bf[(size_t)row * DIM + col] = (short)f2bf(acc[i][jn][r] + bv);
      }
    }
}

// Fused 32-row tile: z = x@W2 + b2 + H1[batch]; att = sigmoid(z)@w3;
// global_rep += segsum(x*att). 17 KB LDS, bitmask segsum, store-vs-atomic.
__global__ __launch_bounds__(256, 5) void k_fused32(
    const char* __restrict__ xbf16p, const int* __restrict__ batch,
    const short* __restrict__ W2t, const float* __restrict__ b2,
    const float* __restrict__ w3, const short* __restrict__ H1bf,
    float* __restrict__ global_rep)
{
  __shared__ __align__(16) short xs[TILE32_B / 2];  // 17408 B incl 512 B DMA pad
  __shared__ int   seg_s[32];
  __shared__ float att_s[32];
  const int tid = threadIdx.x;
  const int bid = (int)blockIdx.x;
  const int row0 = bid * 32;
  const int lane = tid & 63, wave = tid >> 6;
  const int lane15 = lane & 15, quad = lane >> 4;
  const int n0 = wave * 64;

  // async DMA the 17408-B padded tile image: 17 chunks of 1024 B
  {
    const char* gtile = xbf16p + (size_t)bid * TILE32_B;
    char* lbase = (char*)xs;
#pragma unroll
    for (int j = 0; j < 5; ++j) {
      int c = wave + 4 * j;
      if (c < 17)
        GLD16(gtile + (size_t)c * 1024 + lane * 16, lbase + c * 1024);
    }
  }
  if (tid < 32) {
    seg_s[tid] = batch[row0 + tid];
    att_s[tid] = 0.f;
  }
  const int segprev = (row0 > 0) ? batch[row0 - 1] : -1;
  const int segnext = (row0 + 32 < NROWS) ? batch[row0 + 32] : -1;
  // hoist loop-invariant epilogue inputs (independent of DMA)
  float b2v[4], w3v[4];
#pragma unroll
  for (int jn = 0; jn < 4; ++jn) {
    int col = n0 + jn * 16 + lane15;
    b2v[jn] = b2[col];
    w3v[jn] = w3[col];
  }
  __syncthreads();   // drains vmcnt (global_load_lds) + lds writes

  // uniform boundary bitmask (identical in every wave)
  unsigned bmask = (unsigned)__ballot(lane > 0 && lane < 32 &&
                                      seg_s[lane] != seg_s[lane - 1]);

  // prefetch H1 for this thread's first segment; hides under MFMA
  int prev_seg = seg_s[quad * 4];
  float h[4];
#pragma unroll
  for (int jn = 0; jn < 4; ++jn)
    h[jn] = bf2f(H1bf[(size_t)prev_seg * DIM + n0 + jn * 16 + lane15]);

  floatx4 acc[2][4];
#pragma unroll
  for (int i = 0; i < 2; ++i)
#pragma unroll
    for (int j = 0; j < 4; ++j) acc[i][j] = (floatx4)0.f;
  mfma_pass32(xs, W2t, acc, lane15, quad, n0);

  // epilogue: z -> sigmoid -> dot w3 -> att per row (seg-cached H1 gather)
  float part[2][4];
#pragma unroll
  for (int i = 0; i < 2; ++i)
#pragma unroll
    for (int r = 0; r < 4; ++r) {
      int rl = i * 16 + quad * 4 + r;
      int seg = seg_s[rl];
      if (seg != prev_seg) {
#pragma unroll
        for (int jn = 0; jn < 4; ++jn)
          h[jn] = bf2f(H1bf[(size_t)seg * DIM + n0 + jn * 16 + lane15]);
        prev_seg = seg;
      }
      float p = 0.f;
#pragma unroll
      for (int jn = 0; jn < 4; ++jn) {
        float z = acc[i][jn][r] + h[jn] + b2v[jn];
        float sg = __builtin_amdgcn_rcpf(1.0f + __expf(-z));
        p = fmaf(sg, w3v[jn], p);
      }
      part[i][r] = p;
    }
  // reduce over the 16 lanes (cols) of each quad
#pragma unroll
  for (int off = 1; off < 16; off <<= 1)
#pragma unroll
    for (int i = 0; i < 2; ++i)
#pragma unroll
      for (int r = 0; r < 4; ++r)
        part[i][r] += __shfl_xor(part[i][r], off, 64);
  if (lane15 == 0) {
#pragma unroll
    for (int i = 0; i < 2; ++i)
#pragma unroll
      for (int r = 0; r < 4; ++r)
        atomicAdd(&att_s[i * 16 + quad * 4 + r], part[i][r]);
  }
  __syncthreads();

  // phase 2: weighted segsum of x*att from LDS (bf16 x), 32 rows, bitmask-driven
  const int col = tid;
  float acc2 = 0.f;
  int cur = seg_s[0];
#pragma unroll
  for (int r = 0; r < 32; ++r) {
    if (bmask & (1u << r)) {         // uniform branch, rare
      seg_flush(global_rep, cur, col, acc2, segprev, segnext);
      acc2 = 0.f; cur = seg_s[r];
    }
    acc2 = fmaf(bf2f(xs[r * LDSP + col]), att_s[r], acc2);
  }
  seg_flush(global_rep, cur, col, acc2, segprev, segnext);
}

// out = local_rep @ W4[0:256] + global_rep @ W4[256:512] + b4
__global__ __launch_bounds__(256) void k_out_mfma(
    const float* __restrict__ local_rep, const float* __restrict__ global_rep,
    const short* __restrict__ W4t, const float* __restrict__ b4,
    float* __restrict__ out)
{
  __shared__ __align__(16) short xs[64 * LDSP];
  const int tid = threadIdx.x;
  const int row0 = (int)blockIdx.x * 64;
  const int lane = tid & 63, wave = tid >> 6;
  const int lane15 = lane & 15, quad = lane >> 4;
  const int n0 = wave * 64;
  floatx4 acc[4][4];
#pragma unroll
  for (int i = 0; i < 4; ++i)
#pragma unroll
    for (int j = 0; j < 4; ++j) acc[i][j] = (floatx4)0.f;

  stage_tile(local_rep, row0, BSEG - 1, xs, tid);
  __syncthreads();
  mfma_pass(xs, W4t, acc, lane15, quad, n0);
  __syncthreads();
  stage_tile(global_rep, row0, BSEG - 1, xs, tid);
  __syncthreads();
  mfma_pass(xs, W4t + (size_t)8 * 8192, acc, lane15, quad, n0);

#pragma unroll
  for (int i = 0; i < 4; ++i)
#pragma unroll
    for (int jn = 0; jn < 4; ++jn) {
      int col = n0 + jn * 16 + lane15;
      float bv = b4[col];
#pragma unroll
      for (int r = 0; r < 4; ++r) {
        int row = row0 + i * 16 + quad * 4 + r;
        out[(size_t)row * DIM + col] = acc[i][jn][r] + bv;
      }
    }
}

extern "C" void kernel_launch(void* const* d_in, const int* in_sizes, int n_in,
                              void* d_out, int out_size, void* d_ws, size_t ws_size,
                              hipStream_t stream) {
  (void)in_sizes; (void)n_in; (void)out_size; (void)ws_size;
  const float* x    = (const float*)d_in[0];
  const int*   batch= (const int*)d_in[1];
  const float* mask = (const float*)d_in[2];
  const float* W1 = (const float*)d_in[4];
  const float* b1 = (const float*)d_in[5];
  const float* W2 = (const float*)d_in[6];
  const float* b2 = (const float*)d_in[7];
  const float* w3 = (const float*)d_in[8];
  const float* W4 = (const float*)d_in[9];
  const float* b4 = (const float*)d_in[10];
  float* out = (float*)d_out;

  char* base = (char*)d_ws;
  float* local_rep  = (float*)(base);
  float* global_rep = (float*)(base + (size_t)16 * 1024 * 1024);
  short* H1bf       = (short*)(base + (size_t)32 * 1024 * 1024);
  short* W1t        = (short*)(base + (size_t)40 * 1024 * 1024);
  short* W2t        = (short*)(base + (size_t)40 * 1024 * 1024 + 128 * 1024);
  short* W4t        = (short*)(base + (size_t)40 * 1024 * 1024 + 256 * 1024);
  char*  xbf16p     = base + (size_t)48 * 1024 * 1024;

  // zero local_rep + global_rep (32 MB contiguous) at fill-kernel rate
  hipMemsetAsync(local_rep, 0, (size_t)32 * 1024 * 1024, stream);

  // weight conversion only (32 blocks)
  hipLaunchKernelGGL(k_init, dim3(32), dim3(256), 0, stream,
                     W1, W2, W4, W1t, W2t, W4t);

  // x -> bf16 tile images (direct from regs) + masked segsum, 32-row tiles
  hipLaunchKernelGGL(k_prep32, dim3(NT32), dim3(256), 0, stream,
                     x, batch, mask, xbf16p, local_rep);

  hipLaunchKernelGGL(k_h1_mfma, dim3(BSEG / 64), dim3(256), 0, stream,
                     local_rep, W1t, b1, H1bf);

  hipLaunchKernelGGL(k_fused32, dim3(NT32), dim3(256), 0, stream,
                     xbf16p, batch, W2t, b2, w3, H1bf, global_rep);

  hipLaunchKernelGGL(k_out_mfma, dim3(BSEG / 64), dim3(256), 0, stream,
                     local_rep, global_rep, W4t, b4, out);
}